// Round 10
// baseline (17.552 us; speedup 1.0000x reference)
//
#include <hip/hip_runtime.h>
#include <math.h>

// StridedAttention, 2-tile software-pipelined swapped-QK MFMA.
// Each block: two QB=64 tiles; tile1's K/V/Q fetch hides under tile0's compute.
// B=1, H=16, S=2048, D=64, window ±16 (33 local), stride 32 (64 strided)

typedef __attribute__((ext_vector_type(8))) short bf16x8;   // 8 bf16 = 4 VGPR
typedef __attribute__((ext_vector_type(4))) float f32x4;

constexpr int H = 16, S = 2048, D = 64, W = 16;
constexpr int QB   = 64;
constexpr int NLOC = 96;      // local union rows per tile
constexpr int NT   = 10;      // key tiles of 16 (96 local + 64 strided)
constexpr float S2 = 0.18033688011112042f;   // 0.125*log2(e), folded into Q

constexpr int KSTRIDE = 72;               // K row: 64 bf16 + 8 pad
constexpr int VSTR    = 168;              // V^T row: 160 slots + 8 pad
constexpr int REG     = 160 * KSTRIDE;    // 11520 ushort per region (VT 10752 fits)
constexpr int LDS_U   = 2 * REG;          // 23040 ushort = 46080 B

__device__ __forceinline__ ushort f2bf(float x) {
    union { float f; unsigned u; } t; t.f = x;
    unsigned r = t.u + 0x7fffu + ((t.u >> 16) & 1u);   // RNE
    return (ushort)(r >> 16);
}
__device__ __forceinline__ float bf2f(ushort b) {
    union { float f; unsigned u; } t; t.u = ((unsigned)b) << 16;
    return t.f;
}
__device__ __forceinline__ unsigned pk2(float a, float b) {
    return (unsigned)f2bf(a) | ((unsigned)f2bf(b) << 16);
}
__device__ __forceinline__ bf16x8 cvt8(const float4& a, const float4& b) {
    union { bf16x8 v; unsigned u[4]; } r;
    r.u[0] = pk2(a.x, a.y); r.u[1] = pk2(a.z, a.w);
    r.u[2] = pk2(b.x, b.y); r.u[3] = pk2(b.z, b.w);
    return r.v;
}
__device__ __forceinline__ void cvt_hilo(float4 a, float4 b, bf16x8& hi, bf16x8& lo) {
    const float xs[8] = {a.x * S2, a.y * S2, a.z * S2, a.w * S2,
                         b.x * S2, b.y * S2, b.z * S2, b.w * S2};
    union { bf16x8 v; ushort u[8]; } Hv, Lv;
#pragma unroll
    for (int j = 0; j < 8; ++j) {
        const ushort hb = f2bf(xs[j]);
        Hv.u[j] = hb;
        Lv.u[j] = f2bf(xs[j] - bf2f(hb));
    }
    hi = Hv.v; lo = Lv.v;
}
__device__ __forceinline__ int rowpos(int r, int m0) {
    if (r < NLOC) {
        int p = m0 - W + r;               // clamped rows masked in softmax
        return p < 0 ? 0 : (p > S - 1 ? S - 1 : p);
    }
    return (r - NLOC) * 32;               // strided keys (same for all tiles)
}

// QK^T (swapped) + in-lane exp2 softmax + in-register P pack (r5/r9 validated)
__device__ __forceinline__ void tile_qk_softmax(
    const ushort* __restrict__ kb,
    const bf16x8 qh0, const bf16x8 qh1, const bf16x8 ql0, const bf16x8 ql1,
    const int c, const int g, const int qi, const int m0, bf16x8 pa[5])
{
    f32x4 acc[NT];
#pragma unroll
    for (int t = 0; t < NT; ++t) acc[t] = (f32x4){0.f, 0.f, 0.f, 0.f};
#pragma unroll
    for (int t = 0; t < NT; ++t) {
        const bf16x8 a0 = *(const bf16x8*)&kb[(t * 16 + c) * KSTRIDE + g * 8];
        const bf16x8 a1 = *(const bf16x8*)&kb[(t * 16 + c) * KSTRIDE + g * 8 + 32];
        f32x4 a4 = acc[t];
        a4 = __builtin_amdgcn_mfma_f32_16x16x32_bf16(a0, qh0, a4, 0, 0, 0);
        a4 = __builtin_amdgcn_mfma_f32_16x16x32_bf16(a1, qh1, a4, 0, 0, 0);
        a4 = __builtin_amdgcn_mfma_f32_16x16x32_bf16(a0, ql0, a4, 0, 0, 0);
        a4 = __builtin_amdgcn_mfma_f32_16x16x32_bf16(a1, ql1, a4, 0, 0, 0);
        acc[t] = a4;
    }
#pragma unroll
    for (int t = 0; t < 6; ++t) {
#pragma unroll
        for (int i = 0; i < 4; ++i) {
            const int j = t * 16 + 4 * g + i;
            const bool ok = ((unsigned)(j - qi) <= 32u) &&
                            ((unsigned)(m0 - W + j) < (unsigned)S);
            acc[t][i] = ok ? acc[t][i] : -INFINITY;
        }
    }
    const bool us = (m0 + qi) > W;
#pragma unroll
    for (int t = 6; t < NT; ++t)
#pragma unroll
        for (int i = 0; i < 4; ++i)
            acc[t][i] = us ? acc[t][i] : -INFINITY;

    float m = -INFINITY;
#pragma unroll
    for (int t = 0; t < NT; ++t)
#pragma unroll
        for (int i = 0; i < 4; ++i) m = fmaxf(m, acc[t][i]);
    m = fmaxf(m, __shfl_xor(m, 16));
    m = fmaxf(m, __shfl_xor(m, 32));     // finite: self-key always valid

    float l = 0.f;
#pragma unroll
    for (int t = 0; t < NT; ++t)
#pragma unroll
        for (int i = 0; i < 4; ++i) { acc[t][i] = exp2f(acc[t][i] - m); l += acc[t][i]; }
    l += __shfl_xor(l, 16);
    l += __shfl_xor(l, 32);
    const float inv = 1.0f / l;

    union { bf16x8 v; unsigned u[4]; } pk;
#pragma unroll
    for (int kt = 0; kt < 5; ++kt) {
        pk.u[0] = pk2(acc[2 * kt][0] * inv,     acc[2 * kt][1] * inv);
        pk.u[1] = pk2(acc[2 * kt][2] * inv,     acc[2 * kt][3] * inv);
        pk.u[2] = pk2(acc[2 * kt + 1][0] * inv, acc[2 * kt + 1][1] * inv);
        pk.u[3] = pk2(acc[2 * kt + 1][2] * inv, acc[2 * kt + 1][3] * inv);
        pa[kt] = pk.v;
    }
}

// V^T write at permuted slots (r5 validated): key 32kt+16u+4g2+jj -> 32kt+8g2+4u+jj
__device__ __forceinline__ void vt_write(ushort* __restrict__ vtb,
                                         const unsigned vpk[3][8],
                                         const int ntask, const int tid)
{
#pragma unroll
    for (int tt = 0; tt < 3; ++tt) {
        if (tt < ntask) {
            const int tau = tid + (tt << 8);
            const int rp = tau % 80, ch = tau / 80;
            const int kk = 2 * rp;
            const int kt = kk >> 5, rem = kk & 31;
            const int slot = kt * 32 + ((rem >> 2) & 3) * 8 + (rem >> 4) * 4 + (rem & 3);
#pragma unroll
            for (int j = 0; j < 8; ++j)
                *(unsigned*)&vtb[(ch * 8 + j) * VSTR + slot] = vpk[tt][j];
        }
    }
}

// PV MFMA + store (r5 validated)
__device__ __forceinline__ void tile_pv_store(
    const ushort* __restrict__ vtb, const bf16x8 pa[5],
    const int c, const int g, const int qb, const int m0,
    float* __restrict__ outh)
{
    f32x4 o[4];
#pragma unroll
    for (int dt = 0; dt < 4; ++dt) o[dt] = (f32x4){0.f, 0.f, 0.f, 0.f};
#pragma unroll
    for (int kt = 0; kt < 5; ++kt) {
#pragma unroll
        for (int dt = 0; dt < 4; ++dt) {
            const bf16x8 vb = *(const bf16x8*)&vtb[(dt * 16 + c) * VSTR + kt * 32 + g * 8];
            o[dt] = __builtin_amdgcn_mfma_f32_16x16x32_bf16(pa[kt], vb, o[dt], 0, 0, 0);
        }
    }
#pragma unroll
    for (int i = 0; i < 4; ++i) {
        const int n = m0 + qb + 4 * g + i;
        float* op = outh + (size_t)n * D + c;
#pragma unroll
        for (int dt = 0; dt < 4; ++dt) op[dt * 16] = o[dt][i];
    }
}

__global__ __launch_bounds__(256, 1) void strided_attn_mfma(
    const float* __restrict__ q,
    const float* __restrict__ k,
    const float* __restrict__ v,
    float* __restrict__ out)
{
    __shared__ ushort lds[LDS_U];
    ushort* Areg = lds;            // K0, then VT0 overlay
    ushort* Breg = lds + REG;      // K1, then VT1 overlay

    const int tid  = threadIdx.x;
    const int w    = tid >> 6;
    const int lane = tid & 63;
    const int c    = lane & 15;
    const int g    = lane >> 4;
    // XCD-aware bijective swizzle (256 % 8 == 0): 2 heads per XCD
    const int bid  = blockIdx.x;
    const int swz  = (bid & 7) * 32 + (bid >> 3);
    const int h    = swz >> 4;
    const int n0   = (swz & 15) << 7;    // 128 queries per block
    const int m0   = n0;                 // tile 0 base
    const int m1   = n0 + QB;            // tile 1 base

    const float* __restrict__ qh = q + (size_t)(h * S) * D;
    const float* __restrict__ kh = k + (size_t)(h * S) * D;
    const float* __restrict__ vh = v + (size_t)(h * S) * D;
    float* __restrict__ outh = out + (size_t)(h * S) * D;

    const int ntask = (tid < 128) ? 3 : 2;
    const int qb = w * 16;
    const int qi = qb + c;

    // ======== P0: issue everything for both tiles; stage K0 ========
    // V0 issue
    float4 vr0[3][4];
#pragma unroll
    for (int tt = 0; tt < 3; ++tt) {
        if (tt < ntask) {
            const int tau = tid + (tt << 8);
            const int rp = tau % 80, ch = tau / 80;
            const float* s0 = vh + (size_t)rowpos(2 * rp,     m0) * D + ch * 8;
            const float* s1 = vh + (size_t)rowpos(2 * rp + 1, m0) * D + ch * 8;
            vr0[tt][0] = *(const float4*)s0;
            vr0[tt][1] = *(const float4*)(s0 + 4);
            vr0[tt][2] = *(const float4*)s1;
            vr0[tt][3] = *(const float4*)(s1 + 4);
        }
    }
    // Q0, Q1 raw issue
    const float* q0row = qh + (size_t)(m0 + qb + c) * D;
    const float4 q0a = *(const float4*)(q0row + g * 8);
    const float4 q0b = *(const float4*)(q0row + g * 8 + 4);
    const float4 q0c = *(const float4*)(q0row + 32 + g * 8);
    const float4 q0d = *(const float4*)(q0row + 32 + g * 8 + 4);
    const float* q1row = qh + (size_t)(m1 + qb + c) * D;
    const float4 q1a = *(const float4*)(q1row + g * 8);
    const float4 q1b = *(const float4*)(q1row + g * 8 + 4);
    const float4 q1c = *(const float4*)(q1row + 32 + g * 8);
    const float4 q1d = *(const float4*)(q1row + 32 + g * 8 + 4);
    // V1 issue
    float4 vr1[3][4];
#pragma unroll
    for (int tt = 0; tt < 3; ++tt) {
        if (tt < ntask) {
            const int tau = tid + (tt << 8);
            const int rp = tau % 80, ch = tau / 80;
            const float* s0 = vh + (size_t)rowpos(2 * rp,     m1) * D + ch * 8;
            const float* s1 = vh + (size_t)rowpos(2 * rp + 1, m1) * D + ch * 8;
            vr1[tt][0] = *(const float4*)s0;
            vr1[tt][1] = *(const float4*)(s0 + 4);
            vr1[tt][2] = *(const float4*)s1;
            vr1[tt][3] = *(const float4*)(s1 + 4);
        }
    }

    // stage K0 -> A (load + cvt + write; 1280 tasks, 5 unrolled iters)
#pragma unroll
    for (int it = 0; it < 5; ++it) {
        const int t = tid + (it << 8);
        const int row = t >> 3, ch = t & 7;
        const float* src = kh + (size_t)rowpos(row, m0) * D + ch * 8;
        const float4 a = *(const float4*)src;
        const float4 b = *(const float4*)(src + 4);
        *(bf16x8*)&Areg[row * KSTRIDE + ch * 8] = cvt8(a, b);
    }

    // convert Q frags (S2 folded), pack V0 and V1 to bf16
    bf16x8 q0h0, q0l0, q0h1, q0l1, q1h0, q1l0, q1h1, q1l1;
    cvt_hilo(q0a, q0b, q0h0, q0l0);
    cvt_hilo(q0c, q0d, q0h1, q0l1);
    cvt_hilo(q1a, q1b, q1h0, q1l0);
    cvt_hilo(q1c, q1d, q1h1, q1l1);

    unsigned vpk0[3][8], vpk1[3][8];
#pragma unroll
    for (int tt = 0; tt < 3; ++tt) {
        if (tt < ntask) {
            const float r0[8] = {vr0[tt][0].x, vr0[tt][0].y, vr0[tt][0].z, vr0[tt][0].w,
                                 vr0[tt][1].x, vr0[tt][1].y, vr0[tt][1].z, vr0[tt][1].w};
            const float r1[8] = {vr0[tt][2].x, vr0[tt][2].y, vr0[tt][2].z, vr0[tt][2].w,
                                 vr0[tt][3].x, vr0[tt][3].y, vr0[tt][3].z, vr0[tt][3].w};
            const float s0[8] = {vr1[tt][0].x, vr1[tt][0].y, vr1[tt][0].z, vr1[tt][0].w,
                                 vr1[tt][1].x, vr1[tt][1].y, vr1[tt][1].z, vr1[tt][1].w};
            const float s1[8] = {vr1[tt][2].x, vr1[tt][2].y, vr1[tt][2].z, vr1[tt][2].w,
                                 vr1[tt][3].x, vr1[tt][3].y, vr1[tt][3].z, vr1[tt][3].w};
#pragma unroll
            for (int j = 0; j < 8; ++j) {
                vpk0[tt][j] = pk2(r0[j], r1[j]);
                vpk1[tt][j] = pk2(s0[j], s1[j]);
            }
        }
    }

    // issue K1 raw loads (consumed in P2, ~QK0-duration later)
    float4 k1a[5], k1b[5];
#pragma unroll
    for (int it = 0; it < 5; ++it) {
        const int t = tid + (it << 8);
        const int row = t >> 3, ch = t & 7;
        const float* src = kh + (size_t)rowpos(row, m1) * D + ch * 8;
        k1a[it] = *(const float4*)src;
        k1b[it] = *(const float4*)(src + 4);
    }

    __syncthreads();   // b1: K0 staged

    // ======== P1: QK0 + softmax0 + pa0 (K1/V1 loads in flight) ========
    bf16x8 pa0[5];
    tile_qk_softmax(Areg, q0h0, q0h1, q0l0, q0l1, c, g, qi, m0, pa0);

    __syncthreads();   // b2: A (K0) dead

    // ======== P2: VT0 -> A overlay; K1 cvt -> B ========
    vt_write(Areg, vpk0, ntask, tid);
#pragma unroll
    for (int it = 0; it < 5; ++it) {
        const int t = tid + (it << 8);
        const int row = t >> 3, ch = t & 7;
        *(bf16x8*)&Breg[row * KSTRIDE + ch * 8] = cvt8(k1a[it], k1b[it]);
    }

    __syncthreads();   // b3: VT0 + K1 ready

    // ======== P3: PV0 + store O0; then QK1 + softmax1 + pa1 ========
    tile_pv_store(Areg, pa0, c, g, qb, m0, outh);
    bf16x8 pa1[5];
    tile_qk_softmax(Breg, q1h0, q1h1, q1l0, q1l1, c, g, qi, m1, pa1);

    __syncthreads();   // b4: B (K1) dead

    // ======== P4: VT1 -> B overlay ========
    vt_write(Breg, vpk1, ntask, tid);

    __syncthreads();   // b5: VT1 ready

    // ======== P5: PV1 + store O1 ========
    tile_pv_store(Breg, pa1, c, g, qb, m1, outh);
}

extern "C" void kernel_launch(void* const* d_in, const int* in_sizes, int n_in,
                              void* d_out, int out_size, void* d_ws, size_t ws_size,
                              hipStream_t stream) {
    (void)in_sizes; (void)n_in; (void)d_ws; (void)ws_size; (void)out_size;
    const float* q = (const float*)d_in[0];
    const float* k = (const float*)d_in[1];
    const float* v = (const float*)d_in[2];
    float* out     = (float*)d_out;

    dim3 grid(H * (S / 128));   // 256 blocks (2 tiles each) -> 1 per CU
    dim3 block(256);
    strided_attn_mfma<<<grid, block, 0, stream>>>(q, k, v, out);
}

// Round 11
// 15.320 us; speedup vs baseline: 1.1457x; 1.1457x over previous
//
#include <hip/hip_runtime.h>
#include <math.h>

// StridedAttention, r5 geometry + banded QK (skip fully-masked local tiles)
// + Q direct global->reg. Swapped-QK MFMA, softmax & P fully in-register.
// B=1, H=16, S=2048, D=64, window ±16 (33 local), stride 32 (64 strided)

typedef __attribute__((ext_vector_type(8))) short bf16x8;   // 8 bf16 = 4 VGPR
typedef __attribute__((ext_vector_type(4))) float f32x4;

constexpr int H = 16, S = 2048, D = 64, W = 16;
constexpr int QB   = 64;      // queries per block
constexpr int NLOC = 96;      // staged local rows (union of all 4 waves)
constexpr int NRT  = 7;       // per-wave key tiles: 3 local (banded) + 4 strided
constexpr float S2 = 0.18033688011112042f;   // 0.125*log2(e), folded into Q

constexpr int KSTRIDE = 72;               // K row: 64 bf16 + 8 pad (144 B)
constexpr int VSTR    = 168;              // V^T row: 160 slots + 8 pad (336 B)
constexpr int LDS_U   = 160 * KSTRIDE;    // 11520 ush = 23040 B; V^T (10752) overlays

__device__ __forceinline__ ushort f2bf(float x) {
    union { float f; unsigned u; } t; t.f = x;
    unsigned r = t.u + 0x7fffu + ((t.u >> 16) & 1u);   // RNE
    return (ushort)(r >> 16);
}
__device__ __forceinline__ float bf2f(ushort b) {
    union { float f; unsigned u; } t; t.u = ((unsigned)b) << 16;
    return t.f;
}
__device__ __forceinline__ unsigned pk2(float a, float b) {
    return (unsigned)f2bf(a) | ((unsigned)f2bf(b) << 16);
}
__device__ __forceinline__ bf16x8 cvt8(const float4& a, const float4& b) {
    union { bf16x8 v; unsigned u[4]; } r;
    r.u[0] = pk2(a.x, a.y); r.u[1] = pk2(a.z, a.w);
    r.u[2] = pk2(b.x, b.y); r.u[3] = pk2(b.z, b.w);
    return r.v;
}
__device__ __forceinline__ void cvt_hilo(float4 a, float4 b, bf16x8& hi, bf16x8& lo) {
    const float xs[8] = {a.x * S2, a.y * S2, a.z * S2, a.w * S2,
                         b.x * S2, b.y * S2, b.z * S2, b.w * S2};
    union { bf16x8 v; ushort u[8]; } Hv, Lv;
#pragma unroll
    for (int j = 0; j < 8; ++j) {
        const ushort hb = f2bf(xs[j]);
        Hv.u[j] = hb;
        Lv.u[j] = f2bf(xs[j] - bf2f(hb));
    }
    hi = Hv.v; lo = Lv.v;
}
__device__ __forceinline__ int rowpos(int r, int n0) {
    if (r < NLOC) {
        int p = n0 - W + r;               // clamped rows masked in softmax
        return p < 0 ? 0 : (p > S - 1 ? S - 1 : p);
    }
    return (r - NLOC) * 32;               // strided keys
}

__global__ __launch_bounds__(256, 2) void strided_attn_mfma(
    const float* __restrict__ q,
    const float* __restrict__ k,
    const float* __restrict__ v,
    float* __restrict__ out)
{
    __shared__ ushort lds[LDS_U];         // K [160][72]; V^T [64][168] overlay later

    const int tid  = threadIdx.x;
    const int w    = tid >> 6;
    const int lane = tid & 63;
    const int c    = lane & 15;           // query column within wave's 16
    const int g    = lane >> 4;           // k-chunk
    // XCD-aware bijective swizzle (512 % 8 == 0): 2 heads per XCD
    const int bid  = blockIdx.x;
    const int swz  = (bid & 7) * 64 + (bid >> 3);
    const int h    = swz >> 5;
    const int n0   = (swz & 31) << 6;

    const float* __restrict__ qh = q + (size_t)(h * S) * D;
    const float* __restrict__ kh = k + (size_t)(h * S) * D;
    const float* __restrict__ vh = v + (size_t)(h * S) * D;

    // ---- V prefetch into regs (issue-early). 640 tasks: 2 rows x 8 dims each.
    const int ntask = (tid < 128) ? 3 : 2;
    float4 vreg[3][4];
#pragma unroll
    for (int tt = 0; tt < 3; ++tt) {
        if (tt < ntask) {
            const int tau = tid + (tt << 8);
            const int rp = tau % 80, ch = tau / 80;
            const float* s0 = vh + (size_t)rowpos(2 * rp,     n0) * D + ch * 8;
            const float* s1 = vh + (size_t)rowpos(2 * rp + 1, n0) * D + ch * 8;
            vreg[tt][0] = *(const float4*)s0;
            vreg[tt][1] = *(const float4*)(s0 + 4);
            vreg[tt][2] = *(const float4*)s1;
            vreg[tt][3] = *(const float4*)(s1 + 4);
        }
    }

    // ---- Q direct load (issue-early) ----
    const int qb = w * 16;
    const int qi = qb + c;                // this lane's block-relative query
    const int nq = n0 + qi;
    const float* qrow = qh + (size_t)(n0 + qb + c) * D;
    const float4 qv00 = *(const float4*)(qrow + g * 8);
    const float4 qv01 = *(const float4*)(qrow + g * 8 + 4);
    const float4 qv10 = *(const float4*)(qrow + 32 + g * 8);
    const float4 qv11 = *(const float4*)(qrow + 32 + g * 8 + 4);

    // ---- K staging (coalesced): 1280 tasks of 8 dims, 5 branch-free iters ----
#pragma unroll
    for (int it = 0; it < 5; ++it) {
        const int t = tid + (it << 8);
        const int row = t >> 3, ch = t & 7;
        const float* src = kh + (size_t)rowpos(row, n0) * D + ch * 8;
        const float4 a = *(const float4*)src;
        const float4 b = *(const float4*)(src + 4);
        *(bf16x8*)&lds[row * KSTRIDE + ch * 8] = cvt8(a, b);
    }

    // ---- Q frag convert (S2 folded; overlaps staging latency) ----
    bf16x8 bQH0, bQL0, bQH1, bQL1;
    cvt_hilo(qv00, qv01, bQH0, bQL0);
    cvt_hilo(qv10, qv11, bQH1, bQL1);

    __syncthreads();   // barrier 1: K staged

    // ---- banded QK^T (swapped): 7 tiles = local {w,w+1,w+2} + strided {6..9} ----
    f32x4 acc[NRT];
#pragma unroll
    for (int t = 0; t < NRT; ++t) acc[t] = (f32x4){0.f, 0.f, 0.f, 0.f};
#pragma unroll
    for (int t = 0; t < NRT; ++t) {
        const int gt = (t < 3) ? (w + t) : (t + 3);    // global key tile
        const int kb = (gt * 16 + c) * KSTRIDE + g * 8;
        const bf16x8 a0 = *(const bf16x8*)&lds[kb];
        const bf16x8 a1 = *(const bf16x8*)&lds[kb + 32];
        f32x4 a4 = acc[t];
        a4 = __builtin_amdgcn_mfma_f32_16x16x32_bf16(a0, bQH0, a4, 0, 0, 0);
        a4 = __builtin_amdgcn_mfma_f32_16x16x32_bf16(a1, bQH1, a4, 0, 0, 0);
        a4 = __builtin_amdgcn_mfma_f32_16x16x32_bf16(a0, bQL0, a4, 0, 0, 0);
        a4 = __builtin_amdgcn_mfma_f32_16x16x32_bf16(a1, bQL1, a4, 0, 0, 0);
        acc[t] = a4;
    }

    // ---- softmax in place (exp2 domain; logits pre-scaled via Q) ----
#pragma unroll
    for (int t = 0; t < 3; ++t) {        // local banded tiles: key j = 16(w+t)+4g+i
#pragma unroll
        for (int i = 0; i < 4; ++i) {
            const int j = (w + t) * 16 + 4 * g + i;
            const bool ok = ((unsigned)(j - qi) <= 32u) &&
                            ((unsigned)(n0 - W + j) < (unsigned)S);
            acc[t][i] = ok ? acc[t][i] : -INFINITY;
        }
    }
    const bool us = nq > W;
#pragma unroll
    for (int t = 3; t < NRT; ++t)
#pragma unroll
        for (int i = 0; i < 4; ++i)
            acc[t][i] = us ? acc[t][i] : -INFINITY;

    float m = -INFINITY;
#pragma unroll
    for (int t = 0; t < NRT; ++t)
#pragma unroll
        for (int i = 0; i < 4; ++i) m = fmaxf(m, acc[t][i]);
    m = fmaxf(m, __shfl_xor(m, 16));
    m = fmaxf(m, __shfl_xor(m, 32));     // finite: self-key always valid

    float l = 0.f;
#pragma unroll
    for (int t = 0; t < NRT; ++t)
#pragma unroll
        for (int i = 0; i < 4; ++i) { acc[t][i] = exp2f(acc[t][i] - m); l += acc[t][i]; }
    l += __shfl_xor(l, 16);
    l += __shfl_xor(l, 32);
    const float inv = 1.0f / l;

    // ---- pack P into 4 PV A-frags: local kt-slots {klo,klo+1} + strided {3,4} ----
    // slot s covers global tiles {2s, 2s+1}; tiles outside the band are zero.
    const int klo = w >> 1;
    const bool even = (w & 1) == 0;
    union { bf16x8 v; unsigned u[4]; } paL0, paL1, paS0, paS1;
    if (even) {   // band tiles {w,w+1,w+2} = {2klo, 2klo+1, 2klo+2}
        paL0.u[0] = pk2(acc[0][0] * inv, acc[0][1] * inv);
        paL0.u[1] = pk2(acc[0][2] * inv, acc[0][3] * inv);
        paL0.u[2] = pk2(acc[1][0] * inv, acc[1][1] * inv);
        paL0.u[3] = pk2(acc[1][2] * inv, acc[1][3] * inv);
        paL1.u[0] = pk2(acc[2][0] * inv, acc[2][1] * inv);
        paL1.u[1] = pk2(acc[2][2] * inv, acc[2][3] * inv);
        paL1.u[2] = 0; paL1.u[3] = 0;
    } else {      // band tiles {w,w+1,w+2} = {2klo+1, 2klo+2, 2klo+3}
        paL0.u[0] = 0; paL0.u[1] = 0;
        paL0.u[2] = pk2(acc[0][0] * inv, acc[0][1] * inv);
        paL0.u[3] = pk2(acc[0][2] * inv, acc[0][3] * inv);
        paL1.u[0] = pk2(acc[1][0] * inv, acc[1][1] * inv);
        paL1.u[1] = pk2(acc[1][2] * inv, acc[1][3] * inv);
        paL1.u[2] = pk2(acc[2][0] * inv, acc[2][1] * inv);
        paL1.u[3] = pk2(acc[2][2] * inv, acc[2][3] * inv);
    }
    paS0.u[0] = pk2(acc[3][0] * inv, acc[3][1] * inv);
    paS0.u[1] = pk2(acc[3][2] * inv, acc[3][3] * inv);
    paS0.u[2] = pk2(acc[4][0] * inv, acc[4][1] * inv);
    paS0.u[3] = pk2(acc[4][2] * inv, acc[4][3] * inv);
    paS1.u[0] = pk2(acc[5][0] * inv, acc[5][1] * inv);
    paS1.u[1] = pk2(acc[5][2] * inv, acc[5][3] * inv);
    paS1.u[2] = pk2(acc[6][0] * inv, acc[6][1] * inv);
    paS1.u[3] = pk2(acc[6][2] * inv, acc[6][3] * inv);

    __syncthreads();   // barrier 2: K LDS dead -> V^T overlay safe

    // ---- write V^T at permuted slots: key 32kt+16u+4g2+jj -> slot 32kt+8g2+4u+jj
#pragma unroll
    for (int tt = 0; tt < 3; ++tt) {
        if (tt < ntask) {
            const int tau = tid + (tt << 8);
            const int rp = tau % 80, ch = tau / 80;
            const float r0[8] = {vreg[tt][0].x, vreg[tt][0].y, vreg[tt][0].z, vreg[tt][0].w,
                                 vreg[tt][1].x, vreg[tt][1].y, vreg[tt][1].z, vreg[tt][1].w};
            const float r1[8] = {vreg[tt][2].x, vreg[tt][2].y, vreg[tt][2].z, vreg[tt][2].w,
                                 vreg[tt][3].x, vreg[tt][3].y, vreg[tt][3].z, vreg[tt][3].w};
            const int kk = 2 * rp;
            const int kt = kk >> 5, rem = kk & 31;
            const int slot = kt * 32 + ((rem >> 2) & 3) * 8 + (rem >> 4) * 4 + (rem & 3);
#pragma unroll
            for (int j = 0; j < 8; ++j)
                *(unsigned*)&lds[(ch * 8 + j) * VSTR + slot] = pk2(r0[j], r1[j]);
        }
    }
    __syncthreads();   // barrier 3: V^T visible

    // ---- PV over 4 kt-slots: o[q][d] = P x V; A in-reg, B = V^T ----
    f32x4 o[4];
#pragma unroll
    for (int dt = 0; dt < 4; ++dt) o[dt] = (f32x4){0.f, 0.f, 0.f, 0.f};
#pragma unroll
    for (int dt = 0; dt < 4; ++dt) {
        const int vb = (dt * 16 + c) * VSTR + g * 8;
        const bf16x8 v0 = *(const bf16x8*)&lds[vb + (klo)     * 32];
        const bf16x8 v1 = *(const bf16x8*)&lds[vb + (klo + 1) * 32];
        const bf16x8 v2 = *(const bf16x8*)&lds[vb + 3 * 32];
        const bf16x8 v3 = *(const bf16x8*)&lds[vb + 4 * 32];
        f32x4 od = o[dt];
        od = __builtin_amdgcn_mfma_f32_16x16x32_bf16(paL0.v, v0, od, 0, 0, 0);
        od = __builtin_amdgcn_mfma_f32_16x16x32_bf16(paL1.v, v1, od, 0, 0, 0);
        od = __builtin_amdgcn_mfma_f32_16x16x32_bf16(paS0.v, v2, od, 0, 0, 0);
        od = __builtin_amdgcn_mfma_f32_16x16x32_bf16(paS1.v, v3, od, 0, 0, 0);
        o[dt] = od;
    }

    // ---- store (D row = query qb+4g+i, col c = dim within tile; P pre-normalized)
#pragma unroll
    for (int i = 0; i < 4; ++i) {
        const int n = n0 + qb + 4 * g + i;
        float* op = out + ((size_t)(h * S) + n) * D + c;
#pragma unroll
        for (int dt = 0; dt < 4; ++dt) op[dt * 16] = o[dt][i];
    }
}

extern "C" void kernel_launch(void* const* d_in, const int* in_sizes, int n_in,
                              void* d_out, int out_size, void* d_ws, size_t ws_size,
                              hipStream_t stream) {
    (void)in_sizes; (void)n_in; (void)d_ws; (void)ws_size; (void)out_size;
    const float* q = (const float*)d_in[0];
    const float* k = (const float*)d_in[1];
    const float* v = (const float*)d_in[2];
    float* out     = (float*)d_out;

    dim3 grid(H * (S / QB));   // 512 blocks -> 2 per CU
    dim3 block(256);
    strided_attn_mfma<<<grid, block, 0, stream>>>(q, k, v, out);
}